// Round 4
// baseline (209.782 us; speedup 1.0000x reference)
//
#include <hip/hip_runtime.h>
#include <hip/hip_bf16.h>

typedef __bf16 bf16_t;
typedef __bf16 bf16x8 __attribute__((ext_vector_type(8)));
typedef float f32x4 __attribute__((ext_vector_type(4)));

#define NV 8000   // D*H*W
#define QB 125    // NV / 64

__device__ __forceinline__ bf16x8 cvt_bf16x8(const float* __restrict__ p) {
    float4 a = *reinterpret_cast<const float4*>(p);
    float4 b = *reinterpret_cast<const float4*>(p + 4);
    bf16x8 r;
    r[0] = (bf16_t)a.x; r[1] = (bf16_t)a.y; r[2] = (bf16_t)a.z; r[3] = (bf16_t)a.w;
    r[4] = (bf16_t)b.x; r[5] = (bf16_t)b.y; r[6] = (bf16_t)b.z; r[7] = (bf16_t)b.w;
    return r;
}

// ---------------------------------------------------------------------------
// Kernel 1: fused QKV convs, 16-voxel tiles (grid 2*500 for parallelism).
// A = x^T tile (16 vox x 64 chan, bf16 LDS, swizzled); wave w computes the
// 16 output channels w*16..w*16+15 of Q, K and V.
// D layout: col(lr) = kout_local, row(4g+j) = voxel.
// ---------------------------------------------------------------------------
__global__ __launch_bounds__(256) void qkv_kernel(
    const float* __restrict__ x,
    const float* __restrict__ wq, const float* __restrict__ bq,
    const float* __restrict__ wk, const float* __restrict__ bk,
    const float* __restrict__ wv, const float* __restrict__ bv,
    bf16_t* __restrict__ Q, bf16_t* __restrict__ Kr, bf16_t* __restrict__ Vt)
{
    __shared__ __align__(16) char xb[16 * 128];   // [vox][chan] bf16, swizzled

    const int tid = threadIdx.x;
    const int b  = blockIdx.x / 500;
    const int n0 = (blockIdx.x % 500) * 16;

    {   // stage x tile: thread -> (c, seg); transpose into LDS as bf16
        int c = tid >> 2, seg = tid & 3;
        float4 v4 = *reinterpret_cast<const float4*>(&x[((size_t)b * 64 + c) * NV + n0 + seg * 4]);
        #pragma unroll
        for (int j = 0; j < 4; ++j) {
            int vx = seg * 4 + j;
            *reinterpret_cast<bf16_t*>(xb + vx * 128 + ((c * 2) ^ ((vx & 7) << 4))) =
                (bf16_t)((&v4.x)[j]);
        }
    }
    __syncthreads();

    const int w  = tid >> 6;
    const int lane = tid & 63;
    const int g  = lane >> 4;
    const int lr = lane & 15;

    const bf16x8 xa0 = *reinterpret_cast<const bf16x8*>(
        xb + lr * 128 + ((16 * g) ^ ((lr & 7) << 4)));
    const bf16x8 xa1 = *reinterpret_cast<const bf16x8*>(
        xb + lr * 128 + ((64 + 16 * g) ^ ((lr & 7) << 4)));

    const f32x4 zero4 = {0.f, 0.f, 0.f, 0.f};
    const float QSCALE = 0.125f * 1.44269504088896f;
    const int kout = w * 16 + lr;

    // ---- Q ----
    {
        bf16x8 wb0 = cvt_bf16x8(wq + kout * 64 + 8 * g);
        bf16x8 wb1 = cvt_bf16x8(wq + kout * 64 + 32 + 8 * g);
        f32x4 acc = __builtin_amdgcn_mfma_f32_16x16x32_bf16(xa0, wb0, zero4, 0, 0, 0);
        acc = __builtin_amdgcn_mfma_f32_16x16x32_bf16(xa1, wb1, acc, 0, 0, 0);
        const float bias = bq[kout];
        #pragma unroll
        for (int j = 0; j < 4; ++j)
            Q[((size_t)b * NV + n0 + 4 * g + j) * 64 + kout] = (bf16_t)((acc[j] + bias) * QSCALE);
    }
    // ---- K ----
    {
        bf16x8 wb0 = cvt_bf16x8(wk + kout * 64 + 8 * g);
        bf16x8 wb1 = cvt_bf16x8(wk + kout * 64 + 32 + 8 * g);
        f32x4 acc = __builtin_amdgcn_mfma_f32_16x16x32_bf16(xa0, wb0, zero4, 0, 0, 0);
        acc = __builtin_amdgcn_mfma_f32_16x16x32_bf16(xa1, wb1, acc, 0, 0, 0);
        const float bias = bk[kout];
        #pragma unroll
        for (int j = 0; j < 4; ++j)
            Kr[((size_t)b * NV + n0 + 4 * g + j) * 64 + kout] = (bf16_t)(acc[j] + bias);
    }
    // ---- V (lane holds 4 consecutive n -> packed 8B store) ----
    {
        bf16x8 wb0 = cvt_bf16x8(wv + kout * 64 + 8 * g);
        bf16x8 wb1 = cvt_bf16x8(wv + kout * 64 + 32 + 8 * g);
        f32x4 acc = __builtin_amdgcn_mfma_f32_16x16x32_bf16(xa0, wb0, zero4, 0, 0, 0);
        acc = __builtin_amdgcn_mfma_f32_16x16x32_bf16(xa1, wb1, acc, 0, 0, 0);
        const float bias = bv[kout];
        union { uint2 u2; bf16_t h[4]; } pk;
        #pragma unroll
        for (int j = 0; j < 4; ++j) pk.h[j] = (bf16_t)(acc[j] + bias);
        *reinterpret_cast<uint2*>(&Vt[((size_t)b * 64 + kout) * NV + n0 + 4 * g]) = pk.u2;
    }
}

// ---------------------------------------------------------------------------
// Kernel 2: flash attention, split-K S-way.  Grid = S * 2 * QB blocks,
// s = bid % S (XCD-affine k-ranges).  Reg-prefetch of next K/V tile issued
// AFTER the stage barrier so its vmcnt drain lands at the next iteration's
// first barrier (latency hidden under compute).  Defer-max THR=8.
// Writes unnormalized partial O + per-row (m,l).
// ---------------------------------------------------------------------------
template<int S>
__global__ __launch_bounds__(256) void attn_kernel(
    const bf16_t* __restrict__ Q, const bf16_t* __restrict__ Kr,
    const bf16_t* __restrict__ Vt, float* __restrict__ Op, float* __restrict__ ml)
{
    __shared__ __align__(16) char kt[64 * 128];
    __shared__ __align__(16) char vt[64 * 128];
    __shared__ __align__(16) char pt[64 * 128];

    const int tid  = threadIdx.x;
    const int s    = blockIdx.x % S;
    const int rem  = blockIdx.x / S;
    const int b    = rem / QB;
    const int q0   = (rem % QB) * 64;
    const int t0   = (125 * s) / S;
    const int t1   = (125 * (s + 1)) / S;
    const int w    = tid >> 6;
    const int lane = tid & 63;
    const int g    = lane >> 4;
    const int lr   = lane & 15;

    bf16x8 qa0, qa1;
    {
        const size_t qbase = ((size_t)b * NV + q0 + w * 16 + lr) * 64;
        qa0 = *reinterpret_cast<const bf16x8*>(&Q[qbase + 8 * g]);
        qa1 = *reinterpret_cast<const bf16x8*>(&Q[qbase + 32 + 8 * g]);
    }

    // staging roles: thread -> (srow, sch); covers rows srow and srow+32
    const int srow = tid >> 3;
    const int sch  = tid & 7;
    const int dst0 = srow * 128 + ((sch * 16) ^ ((srow & 7) << 4));
    const int dst1 = (srow + 32) * 128 + ((sch * 16) ^ ((srow & 7) << 4));
    const bf16_t* kp = Kr + (size_t)b * NV * 64;
    const bf16_t* vp = Vt + (size_t)b * 64 * NV;

    uint4 rk0, rk1, rv0, rv1;
    {
        const int m0 = t0 * 64;
        rk0 = *reinterpret_cast<const uint4*>(&kp[(size_t)(m0 + srow) * 64 + sch * 8]);
        rk1 = *reinterpret_cast<const uint4*>(&kp[(size_t)(m0 + srow + 32) * 64 + sch * 8]);
        rv0 = *reinterpret_cast<const uint4*>(&vp[(size_t)srow * NV + m0 + sch * 8]);
        rv1 = *reinterpret_cast<const uint4*>(&vp[(size_t)(srow + 32) * NV + m0 + sch * 8]);
    }

    const f32x4 zero4 = {0.f, 0.f, 0.f, 0.f};
    f32x4 oacc[4];
    float m[4], l[4];
    #pragma unroll
    for (int r = 0; r < 4; ++r) { m[r] = -1e30f; l[r] = 0.f; }
    #pragma unroll
    for (int vf = 0; vf < 4; ++vf) oacc[vf] = zero4;

    for (int t = t0; t < t1; ++t) {
        __syncthreads();   // previous tile fully consumed
        *reinterpret_cast<uint4*>(kt + dst0) = rk0;
        *reinterpret_cast<uint4*>(kt + dst1) = rk1;
        *reinterpret_cast<uint4*>(vt + dst0) = rv0;
        *reinterpret_cast<uint4*>(vt + dst1) = rv1;
        __syncthreads();   // stage visible

        // prefetch next tile (clamped); waits resolve at next iter's barrier
        const int tn = (t + 1 < t1) ? t + 1 : t;
        const int mn = tn * 64;
        uint4 nk0 = *reinterpret_cast<const uint4*>(&kp[(size_t)(mn + srow) * 64 + sch * 8]);
        uint4 nk1 = *reinterpret_cast<const uint4*>(&kp[(size_t)(mn + srow + 32) * 64 + sch * 8]);
        uint4 nv0 = *reinterpret_cast<const uint4*>(&vp[(size_t)srow * NV + mn + sch * 8]);
        uint4 nv1 = *reinterpret_cast<const uint4*>(&vp[(size_t)(srow + 32) * NV + mn + sch * 8]);

        // S = Q K^T
        f32x4 sf[4];
        #pragma unroll
        for (int cf = 0; cf < 4; ++cf) {
            const int row  = cf * 16 + lr;
            const int roff = row * 128;
            const int swz  = (row & 7) << 4;
            sf[cf] = __builtin_amdgcn_mfma_f32_16x16x32_bf16(
                qa0, *reinterpret_cast<const bf16x8*>(kt + roff + ((16 * g) ^ swz)),
                zero4, 0, 0, 0);
            sf[cf] = __builtin_amdgcn_mfma_f32_16x16x32_bf16(
                qa1, *reinterpret_cast<const bf16x8*>(kt + roff + ((64 + 16 * g) ^ swz)),
                sf[cf], 0, 0, 0);
        }

        // online softmax, exp2 domain, defer-max THR=8
        float mx[4];
        #pragma unroll
        for (int r = 0; r < 4; ++r) {
            mx[r] = fmaxf(fmaxf(sf[0][r], sf[1][r]), fmaxf(sf[2][r], sf[3][r]));
            #pragma unroll
            for (int off = 1; off < 16; off <<= 1)
                mx[r] = fmaxf(mx[r], __shfl_xor(mx[r], off, 64));
        }
        bool need = false;
        #pragma unroll
        for (int r = 0; r < 4; ++r) need |= (mx[r] > m[r] + 8.0f);
        if (__any(need)) {
            #pragma unroll
            for (int r = 0; r < 4; ++r) {
                const float mn2 = fmaxf(m[r], mx[r]);
                const float corr = exp2f(m[r] - mn2);
                m[r] = mn2;
                l[r] *= corr;
                #pragma unroll
                for (int vf = 0; vf < 4; ++vf) oacc[vf][r] *= corr;
            }
        }
        #pragma unroll
        for (int r = 0; r < 4; ++r) {
            float ps = 0.f;
            #pragma unroll
            for (int cf = 0; cf < 4; ++cf) {
                float p = exp2f(sf[cf][r] - m[r]);
                sf[cf][r] = p;
                ps += p;
            }
            #pragma unroll
            for (int off = 1; off < 16; off <<= 1)
                ps += __shfl_xor(ps, off, 64);
            l[r] += ps;
        }

        // P -> LDS (bf16, swizzled; wave-private rows, no barrier needed)
        #pragma unroll
        for (int cf = 0; cf < 4; ++cf) {
            #pragma unroll
            for (int r = 0; r < 4; ++r) {
                const int prow = w * 16 + g * 4 + r;
                const int pb = prow * 128 + (((cf * 16 + lr) * 2) ^ ((prow & 7) << 4));
                *reinterpret_cast<bf16_t*>(pt + pb) = (bf16_t)sf[cf][r];
            }
        }

        // O += P V
        #pragma unroll
        for (int ms = 0; ms < 2; ++ms) {
            const int prow = w * 16 + lr;
            bf16x8 pa = *reinterpret_cast<const bf16x8*>(
                pt + prow * 128 + ((ms * 64 + 16 * g) ^ ((prow & 7) << 4)));
            #pragma unroll
            for (int vf = 0; vf < 4; ++vf) {
                const int vrow = vf * 16 + lr;
                bf16x8 vb = *reinterpret_cast<const bf16x8*>(
                    vt + vrow * 128 + ((ms * 64 + 16 * g) ^ ((vrow & 7) << 4)));
                oacc[vf] = __builtin_amdgcn_mfma_f32_16x16x32_bf16(pa, vb, oacc[vf], 0, 0, 0);
            }
        }

        rk0 = nk0; rk1 = nk1; rv0 = nv0; rv1 = nv1;
    }

    // epilogue: unnormalized partial O + (m,l)
    const size_t obase = (size_t)(s * 2 + b) * NV;
    #pragma unroll
    for (int vf = 0; vf < 4; ++vf) {
        #pragma unroll
        for (int r = 0; r < 4; ++r) {
            const int row = q0 + w * 16 + g * 4 + r;
            Op[(obase + row) * 64 + vf * 16 + lr] = oacc[vf][r];
        }
    }
    if (lr == 0) {
        #pragma unroll
        for (int r = 0; r < 4; ++r) {
            const int row = q0 + w * 16 + g * 4 + r;
            ml[(obase + row) * 2]     = m[r];
            ml[(obase + row) * 2 + 1] = l[r];
        }
    }
}

// ---------------------------------------------------------------------------
// Kernel 3: fused split-K combine + output projection.
// Block = (b, a, nf): computes out[b][0..63][a*64 + nf*16 .. +15].
// Phase 1: per-row combine factors al[c][s] = exp2(m_s - M)/L.
// Phase 2: gather O rows 125c+a, combine splits, build bf16 B-tile [r][c].
// Phase 3: MFMA A=wo, B=tile; D col(lr)=r_local, row(4g+j)=o_local.
// ---------------------------------------------------------------------------
template<int S>
__global__ __launch_bounds__(256) void projc_kernel(
    const float* __restrict__ Op, const float* __restrict__ ml,
    const float* __restrict__ wo, const float* __restrict__ bo,
    float* __restrict__ out)
{
    __shared__ __align__(16) char bt[16 * 128];   // [r_local][c] bf16, swizzled
    __shared__ float al[64 * 8];                  // [c][s]

    const int tid = threadIdx.x;
    const int b   = blockIdx.x / 500;
    const int rem = blockIdx.x % 500;
    const int a   = rem >> 2;
    const int nf  = rem & 3;

    if (tid < 64) {
        const int row = 125 * tid + a;
        float M = -1e30f;
        #pragma unroll
        for (int s = 0; s < S; ++s)
            M = fmaxf(M, ml[((size_t)(s * 2 + b) * NV + row) * 2]);
        float L = 0.f, av[S];
        #pragma unroll
        for (int s = 0; s < S; ++s) {
            const float mm = ml[((size_t)(s * 2 + b) * NV + row) * 2];
            const float ll = ml[((size_t)(s * 2 + b) * NV + row) * 2 + 1];
            const float aa = exp2f(mm - M);
            L += ll * aa;
            av[s] = aa;
        }
        const float inv = 1.0f / L;
        #pragma unroll
        for (int s = 0; s < S; ++s) al[tid * 8 + s] = av[s] * inv;
    }
    __syncthreads();

    {   // phase 2: thread -> (c, seg); 4 combined values at r_local=seg*4+j
        const int c = tid >> 2, seg = tid & 3;
        f32x4 acc = {0.f, 0.f, 0.f, 0.f};
        #pragma unroll
        for (int s = 0; s < S; ++s) {
            const f32x4 v = *reinterpret_cast<const f32x4*>(
                &Op[((size_t)(s * 2 + b) * NV + 125 * c + a) * 64 + nf * 16 + seg * 4]);
            acc += al[c * 8 + s] * v;
        }
        #pragma unroll
        for (int j = 0; j < 4; ++j) {
            const int r = seg * 4 + j;
            *reinterpret_cast<bf16_t*>(bt + r * 128 + ((c * 2) ^ ((r & 7) << 4))) =
                (bf16_t)acc[j];
        }
    }
    __syncthreads();

    const int w  = tid >> 6;
    const int lane = tid & 63;
    const int g  = lane >> 4;
    const int lr = lane & 15;

    const int orow = w * 16 + lr;
    const bf16x8 wa0 = cvt_bf16x8(wo + orow * 64 + 8 * g);
    const bf16x8 wa1 = cvt_bf16x8(wo + orow * 64 + 32 + 8 * g);
    const bf16x8 gb0 = *reinterpret_cast<const bf16x8*>(
        bt + lr * 128 + ((16 * g) ^ ((lr & 7) << 4)));
    const bf16x8 gb1 = *reinterpret_cast<const bf16x8*>(
        bt + lr * 128 + ((64 + 16 * g) ^ ((lr & 7) << 4)));

    const f32x4 zero4 = {0.f, 0.f, 0.f, 0.f};
    f32x4 acc = __builtin_amdgcn_mfma_f32_16x16x32_bf16(wa0, gb0, zero4, 0, 0, 0);
    acc = __builtin_amdgcn_mfma_f32_16x16x32_bf16(wa1, gb1, acc, 0, 0, 0);

    const float4 bo4 = *reinterpret_cast<const float4*>(&bo[w * 16 + 4 * g]);
    #pragma unroll
    for (int j = 0; j < 4; ++j) {
        const int o = w * 16 + 4 * g + j;
        out[((size_t)b * 64 + o) * NV + a * 64 + nf * 16 + lr] = acc[j] + (&bo4.x)[j];
    }
}

// ---------------------------------------------------------------------------
extern "C" void kernel_launch(void* const* d_in, const int* in_sizes, int n_in,
                              void* d_out, int out_size, void* d_ws, size_t ws_size,
                              hipStream_t stream)
{
    const float* x  = (const float*)d_in[0];
    const float* wq = (const float*)d_in[1];
    const float* bq = (const float*)d_in[2];
    const float* wk = (const float*)d_in[3];
    const float* bk = (const float*)d_in[4];
    const float* wv = (const float*)d_in[5];
    const float* bv = (const float*)d_in[6];
    const float* wo = (const float*)d_in[7];
    const float* bo = (const float*)d_in[8];
    float* out = (float*)d_out;

    // ws layout: Q(2,048,000) | K(2,048,000) | Vt(2,048,000) | Op(S*4,096,000) | ml(S*128,000)
    char* ws = (char*)d_ws;
    bf16_t* Q  = (bf16_t*)(ws);
    bf16_t* Kr = (bf16_t*)(ws + 2048000);
    bf16_t* Vt = (bf16_t*)(ws + 4096000);

    int S = 8;
    if (ws_size < 6144000ull + 8ull * 4224000ull) S = 4;
    if (ws_size < 6144000ull + 4ull * 4224000ull) S = 2;
    if (ws_size < 6144000ull + 2ull * 4224000ull) S = 1;

    float* Op = (float*)(ws + 6144000);
    float* ml = (float*)(ws + 6144000 + (size_t)S * 4096000);

    qkv_kernel<<<dim3(2 * 500), dim3(256), 0, stream>>>(x, wq, bq, wk, bk, wv, bv, Q, Kr, Vt);

    if (S == 8) {
        attn_kernel<8><<<dim3(8 * 2 * QB), dim3(256), 0, stream>>>(Q, Kr, Vt, Op, ml);
        projc_kernel<8><<<dim3(2 * 500), dim3(256), 0, stream>>>(Op, ml, wo, bo, out);
    } else if (S == 4) {
        attn_kernel<4><<<dim3(4 * 2 * QB), dim3(256), 0, stream>>>(Q, Kr, Vt, Op, ml);
        projc_kernel<4><<<dim3(2 * 500), dim3(256), 0, stream>>>(Op, ml, wo, bo, out);
    } else if (S == 2) {
        attn_kernel<2><<<dim3(2 * 2 * QB), dim3(256), 0, stream>>>(Q, Kr, Vt, Op, ml);
        projc_kernel<2><<<dim3(2 * 500), dim3(256), 0, stream>>>(Op, ml, wo, bo, out);
    } else {
        attn_kernel<1><<<dim3(1 * 2 * QB), dim3(256), 0, stream>>>(Q, Kr, Vt, Op, ml);
        projc_kernel<1><<<dim3(2 * 500), dim3(256), 0, stream>>>(Op, ml, wo, bo, out);
    }
}

// Round 5
// 165.272 us; speedup vs baseline: 1.2693x; 1.2693x over previous
//
#include <hip/hip_runtime.h>
#include <hip/hip_bf16.h>

typedef __bf16 bf16_t;
typedef __bf16 bf16x8 __attribute__((ext_vector_type(8)));
typedef float f32x4 __attribute__((ext_vector_type(4)));

#define NV 8000   // D*H*W
#define QB 125    // NV / 64

__device__ __forceinline__ bf16x8 cvt_bf16x8(const float* __restrict__ p) {
    float4 a = *reinterpret_cast<const float4*>(p);
    float4 b = *reinterpret_cast<const float4*>(p + 4);
    bf16x8 r;
    r[0] = (bf16_t)a.x; r[1] = (bf16_t)a.y; r[2] = (bf16_t)a.z; r[3] = (bf16_t)a.w;
    r[4] = (bf16_t)b.x; r[5] = (bf16_t)b.y; r[6] = (bf16_t)b.z; r[7] = (bf16_t)b.w;
    return r;
}

__device__ __forceinline__ unsigned pack2(float a, float b) {
    union { bf16_t h[2]; unsigned u; } x;
    x.h[0] = (bf16_t)a; x.h[1] = (bf16_t)b;
    return x.u;
}

// sigma permutation: n = 125c + a  ->  sigma = 64a + c.  Q and O partials are
// stored in sigma order so the output-projection gather becomes contiguous.
__device__ __forceinline__ int sigma_of(int n) {
    int c = n / 125, a = n - 125 * c;
    return a * 64 + c;
}

// ---------------------------------------------------------------------------
// Kernel 1: fused QKV convs, 16-voxel tiles (grid 2*500).
// Q stored at sigma(n) (pre-scaled by 1/8*log2e); K at n; Vt[v][n] at n.
// ---------------------------------------------------------------------------
__global__ __launch_bounds__(256) void qkv_kernel(
    const float* __restrict__ x,
    const float* __restrict__ wq, const float* __restrict__ bq,
    const float* __restrict__ wk, const float* __restrict__ bk,
    const float* __restrict__ wv, const float* __restrict__ bv,
    bf16_t* __restrict__ Q, bf16_t* __restrict__ Kr, bf16_t* __restrict__ Vt)
{
    __shared__ __align__(16) char xb[16 * 128];   // [vox][chan] bf16, swizzled

    const int tid = threadIdx.x;
    const int b  = blockIdx.x / 500;
    const int n0 = (blockIdx.x % 500) * 16;

    {   // stage x tile: thread -> (c, seg); transpose into LDS as bf16
        int c = tid >> 2, seg = tid & 3;
        float4 v4 = *reinterpret_cast<const float4*>(&x[((size_t)b * 64 + c) * NV + n0 + seg * 4]);
        #pragma unroll
        for (int j = 0; j < 4; ++j) {
            int vx = seg * 4 + j;
            *reinterpret_cast<bf16_t*>(xb + vx * 128 + ((c * 2) ^ ((vx & 7) << 4))) =
                (bf16_t)((&v4.x)[j]);
        }
    }
    __syncthreads();

    const int w  = tid >> 6;
    const int lane = tid & 63;
    const int g  = lane >> 4;
    const int lr = lane & 15;

    const bf16x8 xa0 = *reinterpret_cast<const bf16x8*>(
        xb + lr * 128 + ((16 * g) ^ ((lr & 7) << 4)));
    const bf16x8 xa1 = *reinterpret_cast<const bf16x8*>(
        xb + lr * 128 + ((64 + 16 * g) ^ ((lr & 7) << 4)));

    const f32x4 zero4 = {0.f, 0.f, 0.f, 0.f};
    const float QSCALE = 0.125f * 1.44269504088896f;
    const int kout = w * 16 + lr;

    // ---- Q (sigma-ordered store) ----
    {
        bf16x8 wb0 = cvt_bf16x8(wq + kout * 64 + 8 * g);
        bf16x8 wb1 = cvt_bf16x8(wq + kout * 64 + 32 + 8 * g);
        f32x4 acc = __builtin_amdgcn_mfma_f32_16x16x32_bf16(xa0, wb0, zero4, 0, 0, 0);
        acc = __builtin_amdgcn_mfma_f32_16x16x32_bf16(xa1, wb1, acc, 0, 0, 0);
        const float bias = bq[kout];
        #pragma unroll
        for (int j = 0; j < 4; ++j) {
            const int sig = sigma_of(n0 + 4 * g + j);
            Q[((size_t)b * NV + sig) * 64 + kout] = (bf16_t)((acc[j] + bias) * QSCALE);
        }
    }
    // ---- K (n-ordered) ----
    {
        bf16x8 wb0 = cvt_bf16x8(wk + kout * 64 + 8 * g);
        bf16x8 wb1 = cvt_bf16x8(wk + kout * 64 + 32 + 8 * g);
        f32x4 acc = __builtin_amdgcn_mfma_f32_16x16x32_bf16(xa0, wb0, zero4, 0, 0, 0);
        acc = __builtin_amdgcn_mfma_f32_16x16x32_bf16(xa1, wb1, acc, 0, 0, 0);
        const float bias = bk[kout];
        #pragma unroll
        for (int j = 0; j < 4; ++j)
            Kr[((size_t)b * NV + n0 + 4 * g + j) * 64 + kout] = (bf16_t)(acc[j] + bias);
    }
    // ---- V (n-ordered, packed 8B store) ----
    {
        bf16x8 wb0 = cvt_bf16x8(wv + kout * 64 + 8 * g);
        bf16x8 wb1 = cvt_bf16x8(wv + kout * 64 + 32 + 8 * g);
        f32x4 acc = __builtin_amdgcn_mfma_f32_16x16x32_bf16(xa0, wb0, zero4, 0, 0, 0);
        acc = __builtin_amdgcn_mfma_f32_16x16x32_bf16(xa1, wb1, acc, 0, 0, 0);
        const float bias = bv[kout];
        union { uint2 u2; bf16_t h[4]; } pk;
        #pragma unroll
        for (int j = 0; j < 4; ++j) pk.h[j] = (bf16_t)(acc[j] + bias);
        *reinterpret_cast<uint2*>(&Vt[((size_t)b * 64 + kout) * NV + n0 + 4 * g]) = pk.u2;
    }
}

// ---------------------------------------------------------------------------
// Kernel 2: flash attention, swapped-operand form.
// S^T = mfma(K, Q): lane (g,lr) holds keys {16cf+4g+j} of query lr ->
// softmax row-reduce is 15 local fmax + 2 shuffles (xor 16/32).
// P packed to bf16 pairs, staged via tiny wave-private LDS (4 b64 writes +
// 2 b128 reads), O^T = mfma(V, P).  Defer-max THR=8.  Split-K S-way.
// ---------------------------------------------------------------------------
template<int S>
__global__ __launch_bounds__(256) void attn_kernel(
    const bf16_t* __restrict__ Q, const bf16_t* __restrict__ Kr,
    const bf16_t* __restrict__ Vt, float* __restrict__ Op, float* __restrict__ ml)
{
    __shared__ __align__(16) char kt[64 * 128];
    __shared__ __align__(16) char vt[64 * 128];
    __shared__ __align__(16) char pt[4 * 2048];   // per-wave 16 q-rows x 128B

    const int tid  = threadIdx.x;
    const int s    = blockIdx.x % S;
    const int rem  = blockIdx.x / S;
    const int b    = rem / QB;
    const int q0   = (rem % QB) * 64;            // sigma-tile base
    const int t0   = (125 * s) / S;
    const int t1   = (125 * (s + 1)) / S;
    const int w    = tid >> 6;
    const int lane = tid & 63;
    const int g    = lane >> 4;
    const int lr   = lane & 15;

    bf16x8 qa0, qa1;
    {
        const size_t qbase = ((size_t)b * NV + q0 + w * 16 + lr) * 64;
        qa0 = *reinterpret_cast<const bf16x8*>(&Q[qbase + 8 * g]);
        qa1 = *reinterpret_cast<const bf16x8*>(&Q[qbase + 32 + 8 * g]);
    }

    // staging roles
    const int srow = tid >> 3;
    const int sch  = tid & 7;
    const int dst0 = srow * 128 + ((sch * 16) ^ ((srow & 7) << 4));
    const int dst1 = (srow + 32) * 128 + ((sch * 16) ^ ((srow & 7) << 4));
    const bf16_t* kp = Kr + (size_t)b * NV * 64;
    const bf16_t* vp = Vt + (size_t)b * 64 * NV;

    uint4 rk0, rk1, rv0, rv1;
    {
        const int m0 = t0 * 64;
        rk0 = *reinterpret_cast<const uint4*>(&kp[(size_t)(m0 + srow) * 64 + sch * 8]);
        rk1 = *reinterpret_cast<const uint4*>(&kp[(size_t)(m0 + srow + 32) * 64 + sch * 8]);
        rv0 = *reinterpret_cast<const uint4*>(&vp[(size_t)srow * NV + m0 + sch * 8]);
        rv1 = *reinterpret_cast<const uint4*>(&vp[(size_t)(srow + 32) * NV + m0 + sch * 8]);
    }

    const f32x4 zero4 = {0.f, 0.f, 0.f, 0.f};
    f32x4 oacc[4];
    float m = -1e30f, l = 0.f;
    #pragma unroll
    for (int vf = 0; vf < 4; ++vf) oacc[vf] = zero4;

    char* ptw = pt + w * 2048 + lr * 128;
    const int xsw = (lr & 7) << 2;               // slot-granularity swizzle

    for (int t = t0; t < t1; ++t) {
        __syncthreads();   // previous tile fully consumed
        *reinterpret_cast<uint4*>(kt + dst0) = rk0;
        *reinterpret_cast<uint4*>(kt + dst1) = rk1;
        *reinterpret_cast<uint4*>(vt + dst0) = rv0;
        *reinterpret_cast<uint4*>(vt + dst1) = rv1;
        __syncthreads();   // stage visible

        // prefetch next tile (clamped)
        const int tn = (t + 1 < t1) ? t + 1 : t;
        const int mn0 = tn * 64;
        uint4 nk0 = *reinterpret_cast<const uint4*>(&kp[(size_t)(mn0 + srow) * 64 + sch * 8]);
        uint4 nk1 = *reinterpret_cast<const uint4*>(&kp[(size_t)(mn0 + srow + 32) * 64 + sch * 8]);
        uint4 nv0 = *reinterpret_cast<const uint4*>(&vp[(size_t)srow * NV + mn0 + sch * 8]);
        uint4 nv1 = *reinterpret_cast<const uint4*>(&vp[(size_t)(srow + 32) * NV + mn0 + sch * 8]);

        // S^T = K Q : D[key][query], lane holds keys 16cf+4g+j, query lr
        f32x4 sf[4];
        #pragma unroll
        for (int cf = 0; cf < 4; ++cf) {
            const int row  = cf * 16 + lr;
            const int roff = row * 128;
            const int swz  = (row & 7) << 4;
            const bf16x8 kb0 = *reinterpret_cast<const bf16x8*>(kt + roff + ((16 * g) ^ swz));
            const bf16x8 kb1 = *reinterpret_cast<const bf16x8*>(kt + roff + ((64 + 16 * g) ^ swz));
            sf[cf] = __builtin_amdgcn_mfma_f32_16x16x32_bf16(kb0, qa0, zero4, 0, 0, 0);
            sf[cf] = __builtin_amdgcn_mfma_f32_16x16x32_bf16(kb1, qa1, sf[cf], 0, 0, 0);
        }

        // row max: 15 local fmax + 2 cross-group shuffles
        float mx;
        {
            f32x4 t01 = sf[0], t23 = sf[2];
            #pragma unroll
            for (int j = 0; j < 4; ++j) {
                t01[j] = fmaxf(sf[0][j], sf[1][j]);
                t23[j] = fmaxf(sf[2][j], sf[3][j]);
            }
            float a0 = fmaxf(fmaxf(t01[0], t01[1]), fmaxf(t01[2], t01[3]));
            float a1 = fmaxf(fmaxf(t23[0], t23[1]), fmaxf(t23[2], t23[3]));
            mx = fmaxf(a0, a1);
        }
        mx = fmaxf(mx, __shfl_xor(mx, 16, 64));
        mx = fmaxf(mx, __shfl_xor(mx, 32, 64));

        if (__any(mx > m + 8.0f)) {
            const float mn2 = fmaxf(m, mx);
            const float corr = exp2f(m - mn2);
            m = mn2;
            l *= corr;
            #pragma unroll
            for (int vf = 0; vf < 4; ++vf) oacc[vf] *= corr;
        }

        // exp2 + partial sum + P pack/stage
        float ps = 0.f;
        #pragma unroll
        for (int cf = 0; cf < 4; ++cf) {
            float p0 = exp2f(sf[cf][0] - m);
            float p1 = exp2f(sf[cf][1] - m);
            float p2 = exp2f(sf[cf][2] - m);
            float p3 = exp2f(sf[cf][3] - m);
            ps += (p0 + p1) + (p2 + p3);
            uint2 pw;
            pw.x = pack2(p0, p1);
            pw.y = pack2(p2, p3);
            const int slot = (8 * cf + 2 * g) ^ xsw;
            *reinterpret_cast<uint2*>(ptw + slot * 4) = pw;
        }
        ps += __shfl_xor(ps, 16, 64);
        ps += __shfl_xor(ps, 32, 64);
        l += ps;

        // O^T += V P : D[v][query]
        #pragma unroll
        for (int ms = 0; ms < 2; ++ms) {
            union { uint4 u; bf16x8 v; } pf;
            pf.u = *reinterpret_cast<const uint4*>(ptw + (((16 * ms + 4 * g) ^ xsw) * 4));
            #pragma unroll
            for (int vf = 0; vf < 4; ++vf) {
                const int vrow = vf * 16 + lr;
                const bf16x8 vb = *reinterpret_cast<const bf16x8*>(
                    vt + vrow * 128 + ((ms * 64 + 16 * g) ^ ((vrow & 7) << 4)));
                oacc[vf] = __builtin_amdgcn_mfma_f32_16x16x32_bf16(vb, pf.v, oacc[vf], 0, 0, 0);
            }
        }

        rk0 = nk0; rk1 = nk1; rv0 = nv0; rv1 = nv1;
    }

    // epilogue: lane owns query q = q0+w*16+lr; oacc[vf][j] = O[q][vf*16+4g+j]
    const size_t obase = (size_t)(s * 2 + b) * NV;
    const int qrow = q0 + w * 16 + lr;
    #pragma unroll
    for (int vf = 0; vf < 4; ++vf) {
        *reinterpret_cast<f32x4*>(&Op[(obase + qrow) * 64 + vf * 16 + 4 * g]) = oacc[vf];
    }
    if (g == 0) {
        float2 t2; t2.x = m; t2.y = l;
        *reinterpret_cast<float2*>(&ml[(obase + qrow) * 2]) = t2;
    }
}

// ---------------------------------------------------------------------------
// Kernel 3: fused split-K combine + output projection (sigma-contiguous).
// Block (b, a): out[b][o][64a+r] = bo[o] + sum_c wo[o][c] * O[sigma=64a+c][r]
// Reads Op rows 64a..64a+63 of each split fully coalesced.
// ---------------------------------------------------------------------------
template<int S>
__global__ __launch_bounds__(256) void projc_kernel(
    const float* __restrict__ Op, const float* __restrict__ ml,
    const float* __restrict__ wo, const float* __restrict__ bo,
    float* __restrict__ out)
{
    __shared__ __align__(16) char bt[64 * 128];   // [r=v][c] bf16, swizzled
    __shared__ float al[64 * 8];                  // [c][s] combine factors

    const int tid = threadIdx.x;
    const int b   = blockIdx.x / 125;
    const int a   = blockIdx.x % 125;

    if (tid < 64) {
        const int row = a * 64 + tid;
        float M = -1e30f;
        #pragma unroll
        for (int s = 0; s < S; ++s)
            M = fmaxf(M, ml[((size_t)(s * 2 + b) * NV + row) * 2]);
        float L = 0.f, av[S];
        #pragma unroll
        for (int s = 0; s < S; ++s) {
            const float mm = ml[((size_t)(s * 2 + b) * NV + row) * 2];
            const float ll = ml[((size_t)(s * 2 + b) * NV + row) * 2 + 1];
            const float aa = exp2f(mm - M);
            L += ll * aa;
            av[s] = aa;
        }
        const float inv = 1.0f / L;
        #pragma unroll
        for (int s = 0; s < S; ++s) al[tid * 8 + s] = av[s] * inv;
    }
    __syncthreads();

    {   // combine splits and transpose into bt: bt[v][c] = O_comb[64a+c][v]
        const int c = tid >> 2, sg = tid & 3;     // 4 threads/row, 16 f32 each
        f32x4 acc[4] = {{0,0,0,0},{0,0,0,0},{0,0,0,0},{0,0,0,0}};
        #pragma unroll
        for (int s = 0; s < S; ++s) {
            const float fac = al[c * 8 + s];
            const float* base = &Op[((size_t)(s * 2 + b) * NV + a * 64 + c) * 64 + sg * 16];
            #pragma unroll
            for (int q = 0; q < 4; ++q)
                acc[q] += fac * *reinterpret_cast<const f32x4*>(base + q * 4);
        }
        #pragma unroll
        for (int q = 0; q < 4; ++q) {
            #pragma unroll
            for (int j = 0; j < 4; ++j) {
                const int v = sg * 16 + q * 4 + j;
                *reinterpret_cast<bf16_t*>(bt + v * 128 + ((c * 2) ^ ((v & 7) << 4))) =
                    (bf16_t)acc[q][j];
            }
        }
    }
    __syncthreads();

    const int w  = tid >> 6;
    const int lane = tid & 63;
    const int g  = lane >> 4;
    const int lr = lane & 15;

    const int orow = w * 16 + lr;
    const bf16x8 wa0 = cvt_bf16x8(wo + orow * 64 + 8 * g);
    const bf16x8 wa1 = cvt_bf16x8(wo + orow * 64 + 32 + 8 * g);
    const float4 bo4 = *reinterpret_cast<const float4*>(&bo[w * 16 + 4 * g]);

    const f32x4 zero4 = {0.f, 0.f, 0.f, 0.f};
    #pragma unroll
    for (int nf = 0; nf < 4; ++nf) {
        const int rrow = nf * 16 + lr;
        const bf16x8 gb0 = *reinterpret_cast<const bf16x8*>(
            bt + rrow * 128 + ((16 * g) ^ ((rrow & 7) << 4)));
        const bf16x8 gb1 = *reinterpret_cast<const bf16x8*>(
            bt + rrow * 128 + ((64 + 16 * g) ^ ((rrow & 7) << 4)));
        f32x4 acc = __builtin_amdgcn_mfma_f32_16x16x32_bf16(wa0, gb0, zero4, 0, 0, 0);
        acc = __builtin_amdgcn_mfma_f32_16x16x32_bf16(wa1, gb1, acc, 0, 0, 0);
        #pragma unroll
        for (int j = 0; j < 4; ++j) {
            const int o = w * 16 + 4 * g + j;
            out[((size_t)b * 64 + o) * NV + a * 64 + nf * 16 + lr] = acc[j] + (&bo4.x)[j];
        }
    }
}

// ---------------------------------------------------------------------------
extern "C" void kernel_launch(void* const* d_in, const int* in_sizes, int n_in,
                              void* d_out, int out_size, void* d_ws, size_t ws_size,
                              hipStream_t stream)
{
    const float* x  = (const float*)d_in[0];
    const float* wq = (const float*)d_in[1];
    const float* bq = (const float*)d_in[2];
    const float* wk = (const float*)d_in[3];
    const float* bk = (const float*)d_in[4];
    const float* wv = (const float*)d_in[5];
    const float* bv = (const float*)d_in[6];
    const float* wo = (const float*)d_in[7];
    const float* bo = (const float*)d_in[8];
    float* out = (float*)d_out;

    // ws layout: Q(2,048,000) | K(2,048,000) | Vt(2,048,000) | Op(S*4,096,000) | ml(S*128,000)
    char* ws = (char*)d_ws;
    bf16_t* Q  = (bf16_t*)(ws);
    bf16_t* Kr = (bf16_t*)(ws + 2048000);
    bf16_t* Vt = (bf16_t*)(ws + 4096000);

    int S = 4;
    if (ws_size < 6144000ull + 4ull * 4224000ull) S = 2;
    if (ws_size < 6144000ull + 2ull * 4224000ull) S = 1;

    float* Op = (float*)(ws + 6144000);
    float* ml = (float*)(ws + 6144000 + (size_t)S * 4096000);

    qkv_kernel<<<dim3(2 * 500), dim3(256), 0, stream>>>(x, wq, bq, wk, bk, wv, bv, Q, Kr, Vt);

    if (S == 4) {
        attn_kernel<4><<<dim3(4 * 2 * QB), dim3(256), 0, stream>>>(Q, Kr, Vt, Op, ml);
        projc_kernel<4><<<dim3(2 * 125), dim3(256), 0, stream>>>(Op, ml, wo, bo, out);
    } else if (S == 2) {
        attn_kernel<2><<<dim3(2 * 2 * QB), dim3(256), 0, stream>>>(Q, Kr, Vt, Op, ml);
        projc_kernel<2><<<dim3(2 * 125), dim3(256), 0, stream>>>(Op, ml, wo, bo, out);
    } else {
        attn_kernel<1><<<dim3(1 * 2 * QB), dim3(256), 0, stream>>>(Q, Kr, Vt, Op, ml);
        projc_kernel<1><<<dim3(2 * 125), dim3(256), 0, stream>>>(Op, ml, wo, bo, out);
    }
}